// Round 6
// baseline (1100.164 us; speedup 1.0000x reference)
//
#include <hip/hip_runtime.h>
#include <math.h>

#define E 16
#define D 64
#define H 128
#define R 4            // n-rows per block
#define ROWS (R * E)   // 64 expert-rows per block

// Swizzled float4-chunk address within a [row][128] LDS buffer:
// chunk' = (col/4) ^ (row & 7). Quarter-strided row groups (rows differing
// in low 3 bits) land on distinct bank groups -> conflict-free b128.
#define SWZ4(row, col) ((row) * H + ((((col) >> 2) ^ ((row) & 7)) << 2))
#define SWZ1(row, col) (SWZ4(row, col) + ((col) & 3))

// ---------------------------------------------------------------------------
// Prep: Wabc[c][j] = Wa + Wb + Wc  (spec_W1 rows 0..127, 128..255, 256..383)
// ---------------------------------------------------------------------------
__global__ void wabc_prep(const float* __restrict__ specW1, float* __restrict__ wabc) {
    int i = blockIdx.x * blockDim.x + threadIdx.x;
    if (i < H * H) {
        wabc[i] = specW1[i] + specW1[H * H + i] + specW1[2 * H * H + i];
    }
}

// ---------------------------------------------------------------------------
// Fused router. Block = 256 threads (4 waves), R=4 n-rows. LDS diet for
// 3 blocks/CU (49 KB): tokens read direct from global (no staging), encoder
// runs in two 32-row passes through a 16 KB h-buffer, small arrays carved
// into the dead h-buffer, XOR-swizzled layouts instead of padding.
// Spec GEMM keeps the dense acc[4][8] tile (128 FMA per 4 ds_read_b128).
// ---------------------------------------------------------------------------
template <bool USE_WABC>
__global__ __launch_bounds__(256, 3)
void router_kernel(const float* __restrict__ tokens,
                   const float* __restrict__ encW1, const float* __restrict__ encB1,
                   const float* __restrict__ encW2, const float* __restrict__ encB2,
                   const float* __restrict__ specW1, const float* __restrict__ specB1,
                   const float* __restrict__ specW2,
                   const float* __restrict__ defW1, const float* __restrict__ defB1,
                   const float* __restrict__ defW2, const float* __restrict__ defB2,
                   const int* __restrict__ fiPtr, const int* __restrict__ tkPtr,
                   const float* __restrict__ wabc,
                   float* __restrict__ out, int N) {
    __shared__ float bufE[ROWS * H];   // 32 KB swizzled: encoded
    __shared__ float bufH[32 * H];     // 16 KB swizzled: enc1 h (per pass) -> carved scratch
    __shared__ float s_lg[ROWS];
    __shared__ float s_dred[R];

    const int tid  = threadIdx.x;
    const int lane = tid & 63;
    const int wq   = tid >> 6;         // wave id
    const int mq   = lane >> 4;        // quarter 0..3
    const int jq   = lane & 15;
    const int j0   = jq * 8;           // 8-col chunk in GEMM stages
    const int n0   = blockIdx.x * R;
    const int fi   = fiPtr[0];

    // ================= encoder: two passes of 32 rows =================
    for (int p = 0; p < 2; p++) {
        const int lr0 = wq * 8 + mq * 2;     // local rows lr0, lr0+1 (0..31)
        const int gr0 = p * 32 + lr0;        // block rows 0..63
        const float* tp[2];
#pragma unroll
        for (int i = 0; i < 2; i++) {
            long row = (long)n0 * E + gr0 + i;
            if (row >= (long)N * E) row = 0;   // clamp; garbage rows never stored
            tp[i] = tokens + row * D;
        }

        // ---- enc1: h = relu(tok @ W1 + b1), K=64; global -> bufH ----
        {
            float acc[2][8];
#pragma unroll
            for (int i = 0; i < 2; i++)
#pragma unroll
                for (int j = 0; j < 8; j++) acc[i][j] = 0.f;
#pragma unroll 2
            for (int k = 0; k < D; k += 4) {
                float4 w[4][2];
#pragma unroll
                for (int kk = 0; kk < 4; kk++) {
                    w[kk][0] = *(const float4*)(encW1 + (k + kk) * H + j0);
                    w[kk][1] = *(const float4*)(encW1 + (k + kk) * H + j0 + 4);
                }
#pragma unroll
                for (int i = 0; i < 2; i++) {
                    float4 a4 = *(const float4*)(tp[i] + k);
                    const float av[4] = {a4.x, a4.y, a4.z, a4.w};
#pragma unroll
                    for (int kk = 0; kk < 4; kk++) {
                        float a = av[kk];
                        acc[i][0] = fmaf(a, w[kk][0].x, acc[i][0]);
                        acc[i][1] = fmaf(a, w[kk][0].y, acc[i][1]);
                        acc[i][2] = fmaf(a, w[kk][0].z, acc[i][2]);
                        acc[i][3] = fmaf(a, w[kk][0].w, acc[i][3]);
                        acc[i][4] = fmaf(a, w[kk][1].x, acc[i][4]);
                        acc[i][5] = fmaf(a, w[kk][1].y, acc[i][5]);
                        acc[i][6] = fmaf(a, w[kk][1].z, acc[i][6]);
                        acc[i][7] = fmaf(a, w[kk][1].w, acc[i][7]);
                    }
                }
            }
            float4 b0 = *(const float4*)(encB1 + j0);
            float4 b1 = *(const float4*)(encB1 + j0 + 4);
#pragma unroll
            for (int i = 0; i < 2; i++) {
                const int lr = lr0 + i;
                float4 o0, o1;
                o0.x = fmaxf(acc[i][0] + b0.x, 0.f);
                o0.y = fmaxf(acc[i][1] + b0.y, 0.f);
                o0.z = fmaxf(acc[i][2] + b0.z, 0.f);
                o0.w = fmaxf(acc[i][3] + b0.w, 0.f);
                o1.x = fmaxf(acc[i][4] + b1.x, 0.f);
                o1.y = fmaxf(acc[i][5] + b1.y, 0.f);
                o1.z = fmaxf(acc[i][6] + b1.z, 0.f);
                o1.w = fmaxf(acc[i][7] + b1.w, 0.f);
                *(float4*)(bufH + SWZ4(lr, j0))     = o0;
                *(float4*)(bufH + SWZ4(lr, j0 + 4)) = o1;
            }
        }
        __syncthreads();

        // ---- enc2: encoded = relu(h @ W2 + b2), K=128; bufH -> bufE ----
        {
            float acc[2][8];
#pragma unroll
            for (int i = 0; i < 2; i++)
#pragma unroll
                for (int j = 0; j < 8; j++) acc[i][j] = 0.f;
#pragma unroll 2
            for (int k = 0; k < H; k += 4) {
                float4 w[4][2];
#pragma unroll
                for (int kk = 0; kk < 4; kk++) {
                    w[kk][0] = *(const float4*)(encW2 + (k + kk) * H + j0);
                    w[kk][1] = *(const float4*)(encW2 + (k + kk) * H + j0 + 4);
                }
#pragma unroll
                for (int i = 0; i < 2; i++) {
                    const int lr = lr0 + i;
                    float4 a4 = *(const float4*)(bufH + SWZ4(lr, k));
                    const float av[4] = {a4.x, a4.y, a4.z, a4.w};
#pragma unroll
                    for (int kk = 0; kk < 4; kk++) {
                        float a = av[kk];
                        acc[i][0] = fmaf(a, w[kk][0].x, acc[i][0]);
                        acc[i][1] = fmaf(a, w[kk][0].y, acc[i][1]);
                        acc[i][2] = fmaf(a, w[kk][0].z, acc[i][2]);
                        acc[i][3] = fmaf(a, w[kk][0].w, acc[i][3]);
                        acc[i][4] = fmaf(a, w[kk][1].x, acc[i][4]);
                        acc[i][5] = fmaf(a, w[kk][1].y, acc[i][5]);
                        acc[i][6] = fmaf(a, w[kk][1].z, acc[i][6]);
                        acc[i][7] = fmaf(a, w[kk][1].w, acc[i][7]);
                    }
                }
            }
            float4 b0 = *(const float4*)(encB2 + j0);
            float4 b1 = *(const float4*)(encB2 + j0 + 4);
#pragma unroll
            for (int i = 0; i < 2; i++) {
                const int gr = gr0 + i;
                float4 o0, o1;
                o0.x = fmaxf(acc[i][0] + b0.x, 0.f);
                o0.y = fmaxf(acc[i][1] + b0.y, 0.f);
                o0.z = fmaxf(acc[i][2] + b0.z, 0.f);
                o0.w = fmaxf(acc[i][3] + b0.w, 0.f);
                o1.x = fmaxf(acc[i][4] + b1.x, 0.f);
                o1.y = fmaxf(acc[i][5] + b1.y, 0.f);
                o1.z = fmaxf(acc[i][6] + b1.z, 0.f);
                o1.w = fmaxf(acc[i][7] + b1.w, 0.f);
                *(float4*)(bufE + SWZ4(gr, j0))     = o0;
                *(float4*)(bufE + SWZ4(gr, j0 + 4)) = o1;
            }
        }
        __syncthreads();
    }

    // carved scratch in the now-dead bufH (4096 floats total)
    float* s_full = bufH;               // [R][H]
    float* s_glob = bufH + 512;         // [R][H]
    float* s_mabs = bufH + 1024;        // [R][H]
    float* s_bias = bufH + 1536;        // [R][H]
    float* s_pB   = bufH + 2048;        // [2][R][H]
    float* s_pD   = bufH + 3072;        // [2][R][H]

    // ---- stats: full, glob mean, mean|delta| (wave wq owns n-row wq) ----
    {
#pragma unroll
        for (int half = 0; half < 2; half++) {
            const int c = lane + half * 64;
            float v[E];
#pragma unroll
            for (int e = 0; e < E; e++) v[e] = bufE[SWZ1(wq * E + e, c)];
            float s = 0.f;
#pragma unroll
            for (int e = 0; e < E; e++) s += v[e];
            float fc = v[fi];
            float ma = 0.f;
#pragma unroll
            for (int e = 0; e < E; e++) ma += fabsf(v[e] - fc);
            s_full[wq * H + c] = fc;
            s_glob[wq * H + c] = s * (1.f / 16.f);
            s_mabs[wq * H + c] = ma * (1.f / 16.f);
        }
    }
    __syncthreads();

    // ---- GEMV partials: bias = full@Wb + glob@Wc; def head (float4 loads) ----
    {
        const int c4 = (tid & 31) * 4;   // 4-col chunk
        const int kh = (tid >> 5) & 1;   // K-half
        const int rr = tid >> 6;         // n-row
        const float* __restrict__ Wb = specW1 + H * H;
        const float* __restrict__ Wc = specW1 + 2 * H * H;
        float accB[4] = {0.f, 0.f, 0.f, 0.f};
        float accD[4] = {0.f, 0.f, 0.f, 0.f};
        for (int cc = 0; cc < 64; cc++) {
            const int c = kh * 64 + cc;
            float4 wb = *(const float4*)(Wb + c * H + c4);
            float4 wc = *(const float4*)(Wc + c * H + c4);
            float4 d0 = *(const float4*)(defW1 + c * H + c4);
            float4 d1 = *(const float4*)(defW1 + (H + c) * H + c4);
            float4 d2 = *(const float4*)(defW1 + (2 * H + c) * H + c4);
            float fv = s_full[rr * H + c];
            float gv = s_glob[rr * H + c];
            float mv = s_mabs[rr * H + c];
            accB[0] = fmaf(fv, wb.x, accB[0]); accB[1] = fmaf(fv, wb.y, accB[1]);
            accB[2] = fmaf(fv, wb.z, accB[2]); accB[3] = fmaf(fv, wb.w, accB[3]);
            accB[0] = fmaf(gv, wc.x, accB[0]); accB[1] = fmaf(gv, wc.y, accB[1]);
            accB[2] = fmaf(gv, wc.z, accB[2]); accB[3] = fmaf(gv, wc.w, accB[3]);
            accD[0] = fmaf(fv, d0.x, accD[0]); accD[1] = fmaf(fv, d0.y, accD[1]);
            accD[2] = fmaf(fv, d0.z, accD[2]); accD[3] = fmaf(fv, d0.w, accD[3]);
            accD[0] = fmaf(gv, d1.x, accD[0]); accD[1] = fmaf(gv, d1.y, accD[1]);
            accD[2] = fmaf(gv, d1.z, accD[2]); accD[3] = fmaf(gv, d1.w, accD[3]);
            accD[0] = fmaf(mv, d2.x, accD[0]); accD[1] = fmaf(mv, d2.y, accD[1]);
            accD[2] = fmaf(mv, d2.z, accD[2]); accD[3] = fmaf(mv, d2.w, accD[3]);
        }
        *(float4*)(s_pB + (kh * R + rr) * H + c4) = make_float4(accB[0], accB[1], accB[2], accB[3]);
        *(float4*)(s_pD + (kh * R + rr) * H + c4) = make_float4(accD[0], accD[1], accD[2], accD[3]);
    }
    __syncthreads();

    // ---- finalize bias + defer logit (wave wq owns n-row wq) ----
    {
        float dv = 0.f;
#pragma unroll
        for (int t = 0; t < 2; t++) {
            const int j = lane + t * 64;
            float pb = s_pB[wq * H + j] + s_pB[(R + wq) * H + j];
            s_bias[wq * H + j] = specB1[j] - pb;
            float pd = defB1[j] + s_pD[wq * H + j] + s_pD[(R + wq) * H + j];
            dv += fmaxf(pd, 0.f) * defW2[j];
        }
#pragma unroll
        for (int off = 32; off; off >>= 1) dv += __shfl_xor(dv, off, 64);
        if (lane == 0) s_dred[wq] = dv;
    }
    __syncthreads();

    // ---- spec GEMM: relu(enc@Wabc + |enc-full|@Wd + bias) -> logits ----
    {
        const int gb = wq * 16 + 4 * mq;  // lane's 4 expert-rows
        float acc[4][8];
#pragma unroll
        for (int i = 0; i < 4; i++)
#pragma unroll
            for (int j = 0; j < 8; j++) acc[i][j] = 0.f;
        const float* __restrict__ Wd = specW1 + 3 * H * H;
#pragma unroll 2
        for (int k = 0; k < H; k += 4) {
            float4 wa[4][2], wd[4][2];
#pragma unroll
            for (int kk = 0; kk < 4; kk++) {
                wd[kk][0] = *(const float4*)(Wd + (k + kk) * H + j0);
                wd[kk][1] = *(const float4*)(Wd + (k + kk) * H + j0 + 4);
                if (USE_WABC) {
                    wa[kk][0] = *(const float4*)(wabc + (k + kk) * H + j0);
                    wa[kk][1] = *(const float4*)(wabc + (k + kk) * H + j0 + 4);
                } else {
                    const float* p = specW1 + (k + kk) * H + j0;
                    float4 x0 = *(const float4*)(p);
                    float4 x1 = *(const float4*)(p + H * H);
                    float4 x2 = *(const float4*)(p + 2 * H * H);
                    wa[kk][0] = make_float4(x0.x + x1.x + x2.x, x0.y + x1.y + x2.y,
                                            x0.z + x1.z + x2.z, x0.w + x1.w + x2.w);
                    x0 = *(const float4*)(p + 4);
                    x1 = *(const float4*)(p + H * H + 4);
                    x2 = *(const float4*)(p + 2 * H * H + 4);
                    wa[kk][1] = make_float4(x0.x + x1.x + x2.x, x0.y + x1.y + x2.y,
                                            x0.z + x1.z + x2.z, x0.w + x1.w + x2.w);
                }
            }
            float4 f4 = *(const float4*)(s_full + wq * H + k);   // broadcast
            const float fv[4] = {f4.x, f4.y, f4.z, f4.w};
#pragma unroll
            for (int i = 0; i < 4; i++) {
                float4 e4 = *(const float4*)(bufE + SWZ4(gb + i, k));
                const float ev[4] = {e4.x, e4.y, e4.z, e4.w};
#pragma unroll
                for (int kk = 0; kk < 4; kk++) {
                    float e = ev[kk];
                    float a = fabsf(e - fv[kk]);
                    acc[i][0] = fmaf(e, wa[kk][0].x, acc[i][0]);
                    acc[i][1] = fmaf(e, wa[kk][0].y, acc[i][1]);
                    acc[i][2] = fmaf(e, wa[kk][0].z, acc[i][2]);
                    acc[i][3] = fmaf(e, wa[kk][0].w, acc[i][3]);
                    acc[i][4] = fmaf(e, wa[kk][1].x, acc[i][4]);
                    acc[i][5] = fmaf(e, wa[kk][1].y, acc[i][5]);
                    acc[i][6] = fmaf(e, wa[kk][1].z, acc[i][6]);
                    acc[i][7] = fmaf(e, wa[kk][1].w, acc[i][7]);
                    acc[i][0] = fmaf(a, wd[kk][0].x, acc[i][0]);
                    acc[i][1] = fmaf(a, wd[kk][0].y, acc[i][1]);
                    acc[i][2] = fmaf(a, wd[kk][0].z, acc[i][2]);
                    acc[i][3] = fmaf(a, wd[kk][0].w, acc[i][3]);
                    acc[i][4] = fmaf(a, wd[kk][1].x, acc[i][4]);
                    acc[i][5] = fmaf(a, wd[kk][1].y, acc[i][5]);
                    acc[i][6] = fmaf(a, wd[kk][1].z, acc[i][6]);
                    acc[i][7] = fmaf(a, wd[kk][1].w, acc[i][7]);
                }
            }
        }
        // epilogue: complete logit per row via 16-lane reduce (spec_b2 dropped)
        float4 bb0 = *(const float4*)(s_bias + wq * H + j0);
        float4 bb1 = *(const float4*)(s_bias + wq * H + j0 + 4);
        float4 w20 = *(const float4*)(specW2 + j0);
        float4 w21 = *(const float4*)(specW2 + j0 + 4);
#pragma unroll
        for (int i = 0; i < 4; i++) {
            float p = 0.f;
            p += fmaxf(acc[i][0] + bb0.x, 0.f) * w20.x;
            p += fmaxf(acc[i][1] + bb0.y, 0.f) * w20.y;
            p += fmaxf(acc[i][2] + bb0.z, 0.f) * w20.z;
            p += fmaxf(acc[i][3] + bb0.w, 0.f) * w20.w;
            p += fmaxf(acc[i][4] + bb1.x, 0.f) * w21.x;
            p += fmaxf(acc[i][5] + bb1.y, 0.f) * w21.y;
            p += fmaxf(acc[i][6] + bb1.z, 0.f) * w21.z;
            p += fmaxf(acc[i][7] + bb1.w, 0.f) * w21.w;
#pragma unroll
            for (int off = 1; off < 16; off <<= 1) p += __shfl_xor(p, off, 64);
            if (jq == 0) s_lg[wq * E + 4 * mq + i] = p;
        }
    }
    __syncthreads();

    // ---- finalize (R threads: one per n-row) ----
    if (tid < R && (n0 + tid) < N) {
        const int r = tid;
        const int n = n0 + r;
        float s = s_dred[r] + defB2[0];
        out[(size_t)N * E + n] = 1.f / (1.f + expf(-s));
        float lg[E];
#pragma unroll
        for (int e = 0; e < E; e++) lg[e] = s_lg[r * E + e];
        int k = tkPtr[0];
        if (k < 1) k = 1;
        if (k > E - 1) k = E - 1;
        unsigned chosen = 0u;
        for (int kk = 0; kk < k; kk++) {
            float bv = -INFINITY;
            int bi = 0;
            for (int e = 0; e < E; e++) {
                if (e == fi || ((chosen >> e) & 1u)) continue;
                float v = lg[e];
                if (v > bv) { bv = v; bi = e; }
            }
            chosen |= (1u << bi);
        }
        float mx = -INFINITY;
        for (int e = 0; e < E; e++)
            if ((chosen >> e) & 1u) { float v = lg[e]; if (v > mx) mx = v; }
        float ssum = 0.f;
        for (int e = 0; e < E; e++)
            if ((chosen >> e) & 1u) ssum += expf(lg[e] - mx);
        float inv = 1.f / ssum;
        for (int e = 0; e < E; e++) {
            float wv = 0.f;
            if ((chosen >> e) & 1u) wv = expf(lg[e] - mx) * inv;
            out[(size_t)n * E + e] = wv;
        }
    }
}

extern "C" void kernel_launch(void* const* d_in, const int* in_sizes, int n_in,
                              void* d_out, int out_size, void* d_ws, size_t ws_size,
                              hipStream_t stream) {
    (void)n_in; (void)out_size;
    const float* tokens = (const float*)d_in[0];
    const float* encW1  = (const float*)d_in[1];
    const float* encB1  = (const float*)d_in[2];
    const float* encW2  = (const float*)d_in[3];
    const float* encB2  = (const float*)d_in[4];
    const float* specW1 = (const float*)d_in[5];
    const float* specB1 = (const float*)d_in[6];
    const float* specW2 = (const float*)d_in[7];
    // d_in[8] = spec_b2 (unused: softmax is shift-invariant)
    const float* defW1  = (const float*)d_in[9];
    const float* defB1  = (const float*)d_in[10];
    const float* defW2  = (const float*)d_in[11];
    const float* defB2  = (const float*)d_in[12];
    const int*   fiPtr  = (const int*)d_in[13];
    const int*   tkPtr  = (const int*)d_in[14];
    float* out = (float*)d_out;

    const int N = in_sizes[0] / (E * D);
    const int grid = (N + R - 1) / R;
    const bool useWs = (d_ws != nullptr) && (ws_size >= (size_t)(H * H * sizeof(float)));

    if (useWs) {
        wabc_prep<<<(H * H + 255) / 256, 256, 0, stream>>>(specW1, (float*)d_ws);
        router_kernel<true><<<grid, 256, 0, stream>>>(
            tokens, encW1, encB1, encW2, encB2, specW1, specB1, specW2,
            defW1, defB1, defW2, defB2, fiPtr, tkPtr, (const float*)d_ws, out, N);
    } else {
        router_kernel<false><<<grid, 256, 0, stream>>>(
            tokens, encW1, encB1, encW2, encB2, specW1, specB1, specW2,
            defW1, defB1, defW2, defB2, fiPtr, tkPtr, nullptr, out, N);
    }
}

// Round 7
// 883.868 us; speedup vs baseline: 1.2447x; 1.2447x over previous
//
#include <hip/hip_runtime.h>
#include <math.h>

#define E 16
#define D 64
#define H 128
#define R 4            // n-rows per block
#define ROWS (R * E)   // 64 expert-rows per block
#define MW 16          // expert-rows per wave

typedef float v2f __attribute__((ext_vector_type(2)));
static __device__ __forceinline__ v2f splat2(float x) { v2f r; r.x = x; r.y = x; return r; }
#define PKFMA(a, w, acc) __builtin_elementwise_fma(splat2(a), (w), (acc))

// ---------------------------------------------------------------------------
// Prep: Wabc[c][j] = Wa + Wb + Wc  (spec_W1 rows 0..127, 128..255, 256..383)
// ---------------------------------------------------------------------------
__global__ void wabc_prep(const float* __restrict__ specW1, float* __restrict__ wabc) {
    int i = blockIdx.x * blockDim.x + threadIdx.x;
    if (i < H * H) {
        wabc[i] = specW1[i] + specW1[H * H + i] + specW1[2 * H * H + i];
    }
}

// ---------------------------------------------------------------------------
// Fused router, champion (R3-bench, 761us) structure + v_pk_fma_f32 packing
// + explicit weight prefetch in the k-loops. Block = 256 threads (4 waves),
// R=4 rows/block; wave wq owns n-row wq (16 expert-rows), lane owns 2 cols.
// Activation reads are wave-uniform LDS broadcasts (conflict-free).
// ---------------------------------------------------------------------------
template <bool USE_WABC>
__global__ __launch_bounds__(256, 2)
void router_kernel(const float* __restrict__ tokens,
                   const float* __restrict__ encW1, const float* __restrict__ encB1,
                   const float* __restrict__ encW2, const float* __restrict__ encB2,
                   const float* __restrict__ specW1, const float* __restrict__ specB1,
                   const float* __restrict__ specW2,
                   const float* __restrict__ defW1, const float* __restrict__ defB1,
                   const float* __restrict__ defW2, const float* __restrict__ defB2,
                   const int* __restrict__ fiPtr, const int* __restrict__ tkPtr,
                   const float* __restrict__ wabc,
                   float* __restrict__ out, int N) {
    __shared__ float bufA[ROWS * H];    // 32 KB: tokens (first 16 KB) -> encoded
    __shared__ float bufB[ROWS * H];    // 32 KB: h -> absdelta
    __shared__ float s_glob[R * H];     // 2 KB
    __shared__ float s_mabs[R * H];     // 2 KB
    __shared__ float s_bias[R * H];     // 2 KB
    __shared__ float s_pB[2 * R * H];   // 4 KB  GEMV partials (bias)
    __shared__ float s_pD[2 * R * H];   // 4 KB  GEMV partials (def)
    __shared__ float s_logits[ROWS];
    __shared__ float s_dred[R];

    const int tid   = threadIdx.x;
    const int n0    = blockIdx.x * R;
    const int fi    = fiPtr[0];
    const int lane  = tid & 63;
    const int wq    = tid >> 6;        // wave 0..3 == n-row in GEMM stages
    const int j0    = lane * 2;        // 0..126 even
    const int mbase = wq * MW;         // expert-row block for GEMM stages

    // ---- stage 1: load tokens (ROWS*D = 4096 floats) into bufA ----
    {
        const size_t base  = (size_t)n0 * (E * D);
        const size_t total = (size_t)N * (E * D);
        float4* dst = (float4*)bufA;
#pragma unroll
        for (int it = 0; it < 4; it++) {
            int f = tid + it * 256;
            size_t off = base + (size_t)f * 4;
            float4 v = make_float4(0.f, 0.f, 0.f, 0.f);
            if (off + 3 < total) v = *(const float4*)(tokens + off);
            dst[f] = v;
        }
    }
    __syncthreads();

    // ---- stage 2: enc1  h = relu(tok @ W1 + b1), K=64; bufA -> bufB ----
    {
        v2f acc[MW];
#pragma unroll
        for (int m = 0; m < MW; m++) { acc[m].x = 0.f; acc[m].y = 0.f; }
        v2f w0 = *(const v2f*)(encW1 + 0 * H + j0);
        v2f w1 = *(const v2f*)(encW1 + 1 * H + j0);
        v2f w2 = *(const v2f*)(encW1 + 2 * H + j0);
        v2f w3 = *(const v2f*)(encW1 + 3 * H + j0);
        for (int k = 0; k < D; k += 4) {
            v2f nw0, nw1, nw2, nw3;
            const int kn = k + 4;
            if (kn < D) {
                nw0 = *(const v2f*)(encW1 + (kn + 0) * H + j0);
                nw1 = *(const v2f*)(encW1 + (kn + 1) * H + j0);
                nw2 = *(const v2f*)(encW1 + (kn + 2) * H + j0);
                nw3 = *(const v2f*)(encW1 + (kn + 3) * H + j0);
            }
#pragma unroll
            for (int m = 0; m < MW; m++) {
                float4 t = *(const float4*)(bufA + (mbase + m) * D + k);
                acc[m] = PKFMA(t.x, w0, acc[m]);
                acc[m] = PKFMA(t.y, w1, acc[m]);
                acc[m] = PKFMA(t.z, w2, acc[m]);
                acc[m] = PKFMA(t.w, w3, acc[m]);
            }
            w0 = nw0; w1 = nw1; w2 = nw2; w3 = nw3;
        }
        float2 b = *(const float2*)(encB1 + j0);
#pragma unroll
        for (int m = 0; m < MW; m++) {
            float2 o;
            o.x = fmaxf(acc[m].x + b.x, 0.f);
            o.y = fmaxf(acc[m].y + b.y, 0.f);
            *(float2*)(bufB + (mbase + m) * H + j0) = o;
        }
    }
    __syncthreads();

    // ---- stage 3: enc2  encoded = relu(h @ W2 + b2), K=128; bufB -> bufA ----
    {
        v2f acc[MW];
#pragma unroll
        for (int m = 0; m < MW; m++) { acc[m].x = 0.f; acc[m].y = 0.f; }
        v2f w0 = *(const v2f*)(encW2 + 0 * H + j0);
        v2f w1 = *(const v2f*)(encW2 + 1 * H + j0);
        v2f w2 = *(const v2f*)(encW2 + 2 * H + j0);
        v2f w3 = *(const v2f*)(encW2 + 3 * H + j0);
        for (int k = 0; k < H; k += 4) {
            v2f nw0, nw1, nw2, nw3;
            const int kn = k + 4;
            if (kn < H) {
                nw0 = *(const v2f*)(encW2 + (kn + 0) * H + j0);
                nw1 = *(const v2f*)(encW2 + (kn + 1) * H + j0);
                nw2 = *(const v2f*)(encW2 + (kn + 2) * H + j0);
                nw3 = *(const v2f*)(encW2 + (kn + 3) * H + j0);
            }
#pragma unroll
            for (int m = 0; m < MW; m++) {
                float4 t = *(const float4*)(bufB + (mbase + m) * H + k);
                acc[m] = PKFMA(t.x, w0, acc[m]);
                acc[m] = PKFMA(t.y, w1, acc[m]);
                acc[m] = PKFMA(t.z, w2, acc[m]);
                acc[m] = PKFMA(t.w, w3, acc[m]);
            }
            w0 = nw0; w1 = nw1; w2 = nw2; w3 = nw3;
        }
        float2 b = *(const float2*)(encB2 + j0);
#pragma unroll
        for (int m = 0; m < MW; m++) {
            float2 o;
            o.x = fmaxf(acc[m].x + b.x, 0.f);
            o.y = fmaxf(acc[m].y + b.y, 0.f);
            *(float2*)(bufA + (mbase + m) * H + j0) = o;
        }
    }
    __syncthreads();

    // ---- stage 4: stats: glob mean, absdelta (bufA -> bufB), mean|delta| ----
    {
        const int r4 = tid >> 6;       // 0..3
        const int cb = tid & 63;
#pragma unroll
        for (int half = 0; half < 2; half++) {
            const int c = cb + half * 64;
            const float* er = bufA + (r4 * E) * H + c;
            float v[E];
#pragma unroll
            for (int e = 0; e < E; e++) v[e] = er[e * H];
            float s = 0.f;
#pragma unroll
            for (int e = 0; e < E; e++) s += v[e];
            float fc = v[fi];
            float ma = 0.f;
#pragma unroll
            for (int e = 0; e < E; e++) {
                float a = fabsf(v[e] - fc);
                bufB[(r4 * E + e) * H + c] = a;
                ma += a;
            }
            s_glob[r4 * H + c] = s * (1.f / 16.f);
            s_mabs[r4 * H + c] = ma * (1.f / 16.f);
        }
    }
    __syncthreads();

    // ---- stage 5+7a: GEMV partials: bias (full@Wb + glob@Wc), def head ----
    {
        const int jp = tid & 63;       // j-pair index
        const int jj = jp * 2;
        const int kh = (tid >> 6) & 1; // K-half
        const int rg = tid >> 7;       // r-group (rows rg*2, rg*2+1)
        const int c0 = kh * 64;
        const float* __restrict__ Wb = specW1 + H * H;
        const float* __restrict__ Wc = specW1 + 2 * H * H;
        v2f accB[2], accD[2];
#pragma unroll
        for (int rl = 0; rl < 2; rl++) {
            accB[rl].x = 0.f; accB[rl].y = 0.f;
            accD[rl].x = 0.f; accD[rl].y = 0.f;
        }
        for (int cc = 0; cc < 64; cc++) {
            const int c = c0 + cc;
            v2f wb = *(const v2f*)(Wb + c * H + jj);
            v2f wc = *(const v2f*)(Wc + c * H + jj);
            v2f d0 = *(const v2f*)(defW1 + c * H + jj);
            v2f d1 = *(const v2f*)(defW1 + (H + c) * H + jj);
            v2f d2 = *(const v2f*)(defW1 + (2 * H + c) * H + jj);
#pragma unroll
            for (int rl = 0; rl < 2; rl++) {
                const int r = rg * 2 + rl;
                float fv = bufA[(r * E + fi) * H + c];
                float gv = s_glob[r * H + c];
                float mv = s_mabs[r * H + c];
                accB[rl] = PKFMA(fv, wb, accB[rl]);
                accB[rl] = PKFMA(gv, wc, accB[rl]);
                accD[rl] = PKFMA(fv, d0, accD[rl]);
                accD[rl] = PKFMA(gv, d1, accD[rl]);
                accD[rl] = PKFMA(mv, d2, accD[rl]);
            }
        }
#pragma unroll
        for (int rl = 0; rl < 2; rl++) {
            const int r = rg * 2 + rl;
            *(float2*)(s_pB + (kh * R + r) * H + jj) = make_float2(accB[rl].x, accB[rl].y);
            *(float2*)(s_pD + (kh * R + r) * H + jj) = make_float2(accD[rl].x, accD[rl].y);
        }
    }
    __syncthreads();

    // ---- stage 5+7b: finalize bias and defer logit (wave wq owns row wq) ----
    {
        float dv = 0.f;
#pragma unroll
        for (int t = 0; t < 2; t++) {
            const int j = lane + t * 64;
            float pb = s_pB[wq * H + j] + s_pB[(R + wq) * H + j];
            s_bias[wq * H + j] = specB1[j] - pb;
            float pd = defB1[j] + s_pD[wq * H + j] + s_pD[(R + wq) * H + j];
            dv += fmaxf(pd, 0.f) * defW2[j];
        }
#pragma unroll
        for (int off = 32; off; off >>= 1) dv += __shfl_xor(dv, off, 64);
        if (lane == 0) s_dred[wq] = dv;
    }
    __syncthreads();

    // ---- stage 6: spec GEMM: relu(enc@Wabc + absd@Wd + bias) -> logits ----
    {
        v2f acc[MW];
#pragma unroll
        for (int m = 0; m < MW; m++) { acc[m].x = 0.f; acc[m].y = 0.f; }
        const float* __restrict__ Wd = specW1 + 3 * H * H;
        if (USE_WABC) {
            v2f wa0 = *(const v2f*)(wabc + 0 * H + j0);
            v2f wa1 = *(const v2f*)(wabc + 1 * H + j0);
            v2f wa2 = *(const v2f*)(wabc + 2 * H + j0);
            v2f wa3 = *(const v2f*)(wabc + 3 * H + j0);
            v2f wd0 = *(const v2f*)(Wd + 0 * H + j0);
            v2f wd1 = *(const v2f*)(Wd + 1 * H + j0);
            v2f wd2 = *(const v2f*)(Wd + 2 * H + j0);
            v2f wd3 = *(const v2f*)(Wd + 3 * H + j0);
            for (int k = 0; k < H; k += 4) {
                v2f na0, na1, na2, na3, nd0, nd1, nd2, nd3;
                const int kn = k + 4;
                if (kn < H) {
                    na0 = *(const v2f*)(wabc + (kn + 0) * H + j0);
                    na1 = *(const v2f*)(wabc + (kn + 1) * H + j0);
                    na2 = *(const v2f*)(wabc + (kn + 2) * H + j0);
                    na3 = *(const v2f*)(wabc + (kn + 3) * H + j0);
                    nd0 = *(const v2f*)(Wd + (kn + 0) * H + j0);
                    nd1 = *(const v2f*)(Wd + (kn + 1) * H + j0);
                    nd2 = *(const v2f*)(Wd + (kn + 2) * H + j0);
                    nd3 = *(const v2f*)(Wd + (kn + 3) * H + j0);
                }
#pragma unroll
                for (int m = 0; m < MW; m++) {
                    float4 ev = *(const float4*)(bufA + (mbase + m) * H + k);
                    float4 av = *(const float4*)(bufB + (mbase + m) * H + k);
                    acc[m] = PKFMA(ev.x, wa0, acc[m]);
                    acc[m] = PKFMA(ev.y, wa1, acc[m]);
                    acc[m] = PKFMA(ev.z, wa2, acc[m]);
                    acc[m] = PKFMA(ev.w, wa3, acc[m]);
                    acc[m] = PKFMA(av.x, wd0, acc[m]);
                    acc[m] = PKFMA(av.y, wd1, acc[m]);
                    acc[m] = PKFMA(av.z, wd2, acc[m]);
                    acc[m] = PKFMA(av.w, wd3, acc[m]);
                }
                wa0 = na0; wa1 = na1; wa2 = na2; wa3 = na3;
                wd0 = nd0; wd1 = nd1; wd2 = nd2; wd3 = nd3;
            }
        } else {
            for (int k = 0; k < H; k += 2) {
                const float* p0 = specW1 + k * H + j0;
                const float* p1 = specW1 + (k + 1) * H + j0;
                v2f a00 = *(const v2f*)(p0);
                v2f a01 = *(const v2f*)(p0 + H * H);
                v2f a02 = *(const v2f*)(p0 + 2 * H * H);
                v2f a10 = *(const v2f*)(p1);
                v2f a11 = *(const v2f*)(p1 + H * H);
                v2f a12 = *(const v2f*)(p1 + 2 * H * H);
                v2f wa0 = a00 + a01 + a02;
                v2f wa1 = a10 + a11 + a12;
                v2f wd0 = *(const v2f*)(Wd + k * H + j0);
                v2f wd1 = *(const v2f*)(Wd + (k + 1) * H + j0);
#pragma unroll
                for (int m = 0; m < MW; m++) {
                    float2 ev = *(const float2*)(bufA + (mbase + m) * H + k);
                    float2 av = *(const float2*)(bufB + (mbase + m) * H + k);
                    acc[m] = PKFMA(ev.x, wa0, acc[m]);
                    acc[m] = PKFMA(ev.y, wa1, acc[m]);
                    acc[m] = PKFMA(av.x, wd0, acc[m]);
                    acc[m] = PKFMA(av.y, wd1, acc[m]);
                }
            }
        }
        float2 bn = *(const float2*)(s_bias + wq * H + j0);
        float2 w2 = *(const float2*)(specW2 + j0);
#pragma unroll
        for (int m = 0; m < MW; m++) {
            float h0 = fmaxf(acc[m].x + bn.x, 0.f);
            float h1 = fmaxf(acc[m].y + bn.y, 0.f);
            float p  = h0 * w2.x + h1 * w2.y;   // spec_b2 dropped: softmax shift-invariant
#pragma unroll
            for (int off = 32; off; off >>= 1) p += __shfl_xor(p, off, 64);
            if (lane == 0) s_logits[mbase + m] = p;
        }
    }
    __syncthreads();

    // ---- stage 8: finalize (R threads: one per n-row) ----
    if (tid < R && (n0 + tid) < N) {
        const int r = tid;
        const int n = n0 + r;
        float s = s_dred[r] + defB2[0];
        out[(size_t)N * E + n] = 1.f / (1.f + expf(-s));
        int k = tkPtr[0];
        if (k < 1) k = 1;
        if (k > E - 1) k = E - 1;
        unsigned chosen = 0u;
        for (int kk = 0; kk < k; kk++) {
            float bv = -INFINITY;
            int bi = 0;
            for (int e = 0; e < E; e++) {
                if (e == fi || ((chosen >> e) & 1u)) continue;
                float v = s_logits[r * E + e];
                if (v > bv) { bv = v; bi = e; }
            }
            chosen |= (1u << bi);
        }
        float mx = -INFINITY;
        for (int e = 0; e < E; e++)
            if ((chosen >> e) & 1u) { float v = s_logits[r * E + e]; if (v > mx) mx = v; }
        float ssum = 0.f;
        for (int e = 0; e < E; e++)
            if ((chosen >> e) & 1u) ssum += expf(s_logits[r * E + e] - mx);
        float inv = 1.f / ssum;
        for (int e = 0; e < E; e++) {
            float wv = 0.f;
            if ((chosen >> e) & 1u) wv = expf(s_logits[r * E + e] - mx) * inv;
            out[(size_t)n * E + e] = wv;
        }
    }
}

extern "C" void kernel_launch(void* const* d_in, const int* in_sizes, int n_in,
                              void* d_out, int out_size, void* d_ws, size_t ws_size,
                              hipStream_t stream) {
    (void)n_in; (void)out_size;
    const float* tokens = (const float*)d_in[0];
    const float* encW1  = (const float*)d_in[1];
    const float* encB1  = (const float*)d_in[2];
    const float* encW2  = (const float*)d_in[3];
    const float* encB2  = (const float*)d_in[4];
    const float* specW1 = (const float*)d_in[5];
    const float* specB1 = (const float*)d_in[6];
    const float* specW2 = (const float*)d_in[7];
    // d_in[8] = spec_b2 (unused: softmax is shift-invariant)
    const float* defW1  = (const float*)d_in[9];
    const float* defB1  = (const float*)d_in[10];
    const float* defW2  = (const float*)d_in[11];
    const float* defB2  = (const float*)d_in[12];
    const int*   fiPtr  = (const int*)d_in[13];
    const int*   tkPtr  = (const int*)d_in[14];
    float* out = (float*)d_out;

    const int N = in_sizes[0] / (E * D);
    const int grid = (N + R - 1) / R;
    const bool useWs = (d_ws != nullptr) && (ws_size >= (size_t)(H * H * sizeof(float)));

    if (useWs) {
        wabc_prep<<<(H * H + 255) / 256, 256, 0, stream>>>(specW1, (float*)d_ws);
        router_kernel<true><<<grid, 256, 0, stream>>>(
            tokens, encW1, encB1, encW2, encB2, specW1, specB1, specW2,
            defW1, defB1, defW2, defB2, fiPtr, tkPtr, (const float*)d_ws, out, N);
    } else {
        router_kernel<false><<<grid, 256, 0, stream>>>(
            tokens, encW1, encB1, encW2, encB2, specW1, specB1, specW2,
            defW1, defB1, defW2, defB2, fiPtr, tkPtr, nullptr, out, N);
    }
}

// Round 8
// 739.453 us; speedup vs baseline: 1.4878x; 1.1953x over previous
//
#include <hip/hip_runtime.h>
#include <math.h>

#define E 16
#define D 64
#define H 128
#define R 4            // n-rows per block
#define ROWS (R * E)   // 64 expert-rows per block
#define MW 16          // expert-rows per wave

// ---------------------------------------------------------------------------
// Prep: Wabc[c][j] = Wa + Wb + Wc  (spec_W1 rows 0..127, 128..255, 256..383)
// ---------------------------------------------------------------------------
__global__ void wabc_prep(const float* __restrict__ specW1, float* __restrict__ wabc) {
    int i = blockIdx.x * blockDim.x + threadIdx.x;
    if (i < H * H) {
        wabc[i] = specW1[i] + specW1[H * H + i] + specW1[2 * H * H + i];
    }
}

// ---------------------------------------------------------------------------
// Fused router. Block = 256 threads (4 waves), R=4; wave wq owns n-row wq
// (16 expert-rows). GEMM stages use half-wave j4 tiling: lane = (hw, jl),
// hw = lane>>5 picks rows mbase+hw*8..+7, jl*4 = 4-col chunk. Activation
// reads are 2-address b128 broadcasts (2-way = free); one read feeds 32
// FMAs. Stage 6 computes |enc - full| on the fly (no absdelta buffer), so
// bufB is dead after enc2 and hosts the GEMV partials. LDS ~74 KB.
// ---------------------------------------------------------------------------
template <bool USE_WABC>
__global__ __launch_bounds__(256, 2)
void router_kernel(const float* __restrict__ tokens,
                   const float* __restrict__ encW1, const float* __restrict__ encB1,
                   const float* __restrict__ encW2, const float* __restrict__ encB2,
                   const float* __restrict__ specW1, const float* __restrict__ specB1,
                   const float* __restrict__ specW2,
                   const float* __restrict__ defW1, const float* __restrict__ defB1,
                   const float* __restrict__ defW2, const float* __restrict__ defB2,
                   const int* __restrict__ fiPtr, const int* __restrict__ tkPtr,
                   const float* __restrict__ wabc,
                   float* __restrict__ out, int N) {
    __shared__ float bufA[ROWS * H];    // 32 KB: tokens (first 16 KB) -> encoded
    __shared__ float bufB[ROWS * H];    // 32 KB: h; after enc2: GEMV partial scratch
    __shared__ float s_full[R * H];     // 2 KB
    __shared__ float s_glob[R * H];     // 2 KB
    __shared__ float s_mabs[R * H];     // 2 KB
    __shared__ float s_bias[R * H];     // 2 KB
    __shared__ float s_logits[ROWS];
    __shared__ float s_dred[R];

    const int tid   = threadIdx.x;
    const int n0    = blockIdx.x * R;
    const int fi    = fiPtr[0];
    const int lane  = tid & 63;
    const int wq    = tid >> 6;        // wave 0..3 == n-row in GEMM stages
    const int mbase = wq * MW;
    const int hw    = lane >> 5;       // half-wave 0/1 -> row-halves
    const int jl    = lane & 31;
    const int jw0   = jl * 4;          // this lane's 4-col chunk
    const int mb2   = mbase + hw * 8;  // first of this lane's 8 rows

    // ---- stage 1: load tokens (ROWS*D = 4096 floats) into bufA ----
    {
        const size_t base  = (size_t)n0 * (E * D);
        const size_t total = (size_t)N * (E * D);
        float4* dst = (float4*)bufA;
#pragma unroll
        for (int it = 0; it < 4; it++) {
            int f = tid + it * 256;
            size_t off = base + (size_t)f * 4;
            float4 v = make_float4(0.f, 0.f, 0.f, 0.f);
            if (off + 3 < total) v = *(const float4*)(tokens + off);
            dst[f] = v;
        }
    }
    __syncthreads();

    // ---- stage 2: enc1  h = relu(tok @ W1 + b1), K=64; bufA -> bufB ----
    {
        float acc[8][4];
#pragma unroll
        for (int m = 0; m < 8; m++)
#pragma unroll
            for (int j = 0; j < 4; j++) acc[m][j] = 0.f;
#pragma unroll 2
        for (int k = 0; k < D; k += 4) {
            float4 w0 = *(const float4*)(encW1 + (k + 0) * H + jw0);
            float4 w1 = *(const float4*)(encW1 + (k + 1) * H + jw0);
            float4 w2 = *(const float4*)(encW1 + (k + 2) * H + jw0);
            float4 w3 = *(const float4*)(encW1 + (k + 3) * H + jw0);
#pragma unroll
            for (int m = 0; m < 8; m++) {
                float4 t = *(const float4*)(bufA + (mb2 + m) * D + k);
                acc[m][0] = fmaf(t.w, w3.x, fmaf(t.z, w2.x, fmaf(t.y, w1.x, fmaf(t.x, w0.x, acc[m][0]))));
                acc[m][1] = fmaf(t.w, w3.y, fmaf(t.z, w2.y, fmaf(t.y, w1.y, fmaf(t.x, w0.y, acc[m][1]))));
                acc[m][2] = fmaf(t.w, w3.z, fmaf(t.z, w2.z, fmaf(t.y, w1.z, fmaf(t.x, w0.z, acc[m][2]))));
                acc[m][3] = fmaf(t.w, w3.w, fmaf(t.z, w2.w, fmaf(t.y, w1.w, fmaf(t.x, w0.w, acc[m][3]))));
            }
        }
        float4 b = *(const float4*)(encB1 + jw0);
#pragma unroll
        for (int m = 0; m < 8; m++) {
            float4 o;
            o.x = fmaxf(acc[m][0] + b.x, 0.f);
            o.y = fmaxf(acc[m][1] + b.y, 0.f);
            o.z = fmaxf(acc[m][2] + b.z, 0.f);
            o.w = fmaxf(acc[m][3] + b.w, 0.f);
            *(float4*)(bufB + (mb2 + m) * H + jw0) = o;
        }
    }
    __syncthreads();

    // ---- stage 3: enc2  encoded = relu(h @ W2 + b2), K=128; bufB -> bufA ----
    {
        float acc[8][4];
#pragma unroll
        for (int m = 0; m < 8; m++)
#pragma unroll
            for (int j = 0; j < 4; j++) acc[m][j] = 0.f;
#pragma unroll 2
        for (int k = 0; k < H; k += 4) {
            float4 w0 = *(const float4*)(encW2 + (k + 0) * H + jw0);
            float4 w1 = *(const float4*)(encW2 + (k + 1) * H + jw0);
            float4 w2 = *(const float4*)(encW2 + (k + 2) * H + jw0);
            float4 w3 = *(const float4*)(encW2 + (k + 3) * H + jw0);
#pragma unroll
            for (int m = 0; m < 8; m++) {
                float4 t = *(const float4*)(bufB + (mb2 + m) * H + k);
                acc[m][0] = fmaf(t.w, w3.x, fmaf(t.z, w2.x, fmaf(t.y, w1.x, fmaf(t.x, w0.x, acc[m][0]))));
                acc[m][1] = fmaf(t.w, w3.y, fmaf(t.z, w2.y, fmaf(t.y, w1.y, fmaf(t.x, w0.y, acc[m][1]))));
                acc[m][2] = fmaf(t.w, w3.z, fmaf(t.z, w2.z, fmaf(t.y, w1.z, fmaf(t.x, w0.z, acc[m][2]))));
                acc[m][3] = fmaf(t.w, w3.w, fmaf(t.z, w2.w, fmaf(t.y, w1.w, fmaf(t.x, w0.w, acc[m][3]))));
            }
        }
        float4 b = *(const float4*)(encB2 + jw0);
#pragma unroll
        for (int m = 0; m < 8; m++) {
            float4 o;
            o.x = fmaxf(acc[m][0] + b.x, 0.f);
            o.y = fmaxf(acc[m][1] + b.y, 0.f);
            o.z = fmaxf(acc[m][2] + b.z, 0.f);
            o.w = fmaxf(acc[m][3] + b.w, 0.f);
            *(float4*)(bufA + (mb2 + m) * H + jw0) = o;
        }
    }
    __syncthreads();

    // ---- stage 4: stats: full, glob mean, mean|delta| (no absdelta store) ----
    {
        const int r4 = tid >> 6;       // 0..3
        const int cb = tid & 63;
#pragma unroll
        for (int half = 0; half < 2; half++) {
            const int c = cb + half * 64;
            const float* er = bufA + (r4 * E) * H + c;
            float v[E];
#pragma unroll
            for (int e = 0; e < E; e++) v[e] = er[e * H];
            float s = 0.f;
#pragma unroll
            for (int e = 0; e < E; e++) s += v[e];
            float fc = v[fi];
            float ma = 0.f;
#pragma unroll
            for (int e = 0; e < E; e++) ma += fabsf(v[e] - fc);
            s_full[r4 * H + c] = fc;
            s_glob[r4 * H + c] = s * (1.f / 16.f);
            s_mabs[r4 * H + c] = ma * (1.f / 16.f);
        }
    }
    __syncthreads();

    // ---- stage 5+7a: GEMV partials into dead bufB ----
    float* s_pB = bufB;              // [2][R][H] = 1024 floats
    float* s_pD = bufB + 2 * R * H;  // 1024 floats
    {
        const int jp = tid & 63;       // j-pair index
        const int jj = jp * 2;
        const int kh = (tid >> 6) & 1; // K-half
        const int rg = tid >> 7;       // r-group (rows rg*2, rg*2+1)
        const int c0 = kh * 64;
        const float* __restrict__ Wb = specW1 + H * H;
        const float* __restrict__ Wc = specW1 + 2 * H * H;
        float accB[2][2] = {{0.f, 0.f}, {0.f, 0.f}};
        float accD[2][2] = {{0.f, 0.f}, {0.f, 0.f}};
        for (int cc = 0; cc < 64; cc++) {
            const int c = c0 + cc;
            float2 wb = *(const float2*)(Wb + c * H + jj);
            float2 wc = *(const float2*)(Wc + c * H + jj);
            float2 d0 = *(const float2*)(defW1 + c * H + jj);
            float2 d1 = *(const float2*)(defW1 + (H + c) * H + jj);
            float2 d2 = *(const float2*)(defW1 + (2 * H + c) * H + jj);
#pragma unroll
            for (int rl = 0; rl < 2; rl++) {
                const int r = rg * 2 + rl;
                float fv = s_full[r * H + c];
                float gv = s_glob[r * H + c];
                float mv = s_mabs[r * H + c];
                accB[rl][0] = fmaf(fv, wb.x, accB[rl][0]);
                accB[rl][1] = fmaf(fv, wb.y, accB[rl][1]);
                accB[rl][0] = fmaf(gv, wc.x, accB[rl][0]);
                accB[rl][1] = fmaf(gv, wc.y, accB[rl][1]);
                accD[rl][0] = fmaf(fv, d0.x, accD[rl][0]);
                accD[rl][1] = fmaf(fv, d0.y, accD[rl][1]);
                accD[rl][0] = fmaf(gv, d1.x, accD[rl][0]);
                accD[rl][1] = fmaf(gv, d1.y, accD[rl][1]);
                accD[rl][0] = fmaf(mv, d2.x, accD[rl][0]);
                accD[rl][1] = fmaf(mv, d2.y, accD[rl][1]);
            }
        }
#pragma unroll
        for (int rl = 0; rl < 2; rl++) {
            const int r = rg * 2 + rl;
            *(float2*)(s_pB + (kh * R + r) * H + jj) = make_float2(accB[rl][0], accB[rl][1]);
            *(float2*)(s_pD + (kh * R + r) * H + jj) = make_float2(accD[rl][0], accD[rl][1]);
        }
    }
    __syncthreads();

    // ---- stage 5+7b: finalize bias and defer logit (wave wq owns row wq) ----
    {
        float dv = 0.f;
#pragma unroll
        for (int t = 0; t < 2; t++) {
            const int j = lane + t * 64;
            float pb = s_pB[wq * H + j] + s_pB[(R + wq) * H + j];
            s_bias[wq * H + j] = specB1[j] - pb;
            float pd = defB1[j] + s_pD[wq * H + j] + s_pD[(R + wq) * H + j];
            dv += fmaxf(pd, 0.f) * defW2[j];
        }
#pragma unroll
        for (int off = 32; off; off >>= 1) dv += __shfl_xor(dv, off, 64);
        if (lane == 0) s_dred[wq] = dv;
    }
    __syncthreads();

    // ---- stage 6: spec GEMM: relu(enc@Wabc + |enc-full|@Wd + bias) -> logits ----
    {
        float acc[8][4];
#pragma unroll
        for (int m = 0; m < 8; m++)
#pragma unroll
            for (int j = 0; j < 4; j++) acc[m][j] = 0.f;
        const float* __restrict__ Wd = specW1 + 3 * H * H;
        for (int k = 0; k < H; k += 4) {
            float4 wa0, wa1, wa2, wa3;
            if (USE_WABC) {
                wa0 = *(const float4*)(wabc + (k + 0) * H + jw0);
                wa1 = *(const float4*)(wabc + (k + 1) * H + jw0);
                wa2 = *(const float4*)(wabc + (k + 2) * H + jw0);
                wa3 = *(const float4*)(wabc + (k + 3) * H + jw0);
            } else {
#pragma unroll
                for (int t = 0; t < 4; t++) {
                    const float* p = specW1 + (k + t) * H + jw0;
                    float4 x0 = *(const float4*)(p);
                    float4 x1 = *(const float4*)(p + H * H);
                    float4 x2 = *(const float4*)(p + 2 * H * H);
                    float4 s4 = make_float4(x0.x + x1.x + x2.x, x0.y + x1.y + x2.y,
                                            x0.z + x1.z + x2.z, x0.w + x1.w + x2.w);
                    if (t == 0) wa0 = s4; else if (t == 1) wa1 = s4;
                    else if (t == 2) wa2 = s4; else wa3 = s4;
                }
            }
            float4 wd0 = *(const float4*)(Wd + (k + 0) * H + jw0);
            float4 wd1 = *(const float4*)(Wd + (k + 1) * H + jw0);
            float4 wd2 = *(const float4*)(Wd + (k + 2) * H + jw0);
            float4 wd3 = *(const float4*)(Wd + (k + 3) * H + jw0);
            float4 f4 = *(const float4*)(s_full + wq * H + k);   // uniform broadcast
#pragma unroll
            for (int m = 0; m < 8; m++) {
                float4 ev = *(const float4*)(bufA + (mb2 + m) * H + k);
                float ax = fabsf(ev.x - f4.x);
                float ay = fabsf(ev.y - f4.y);
                float az = fabsf(ev.z - f4.z);
                float aw = fabsf(ev.w - f4.w);
#pragma unroll
                for (int j = 0; j < 4; j++) {
                    const float* waj0 = &wa0.x, *waj1 = &wa1.x, *waj2 = &wa2.x, *waj3 = &wa3.x;
                    const float* wdj0 = &wd0.x, *wdj1 = &wd1.x, *wdj2 = &wd2.x, *wdj3 = &wd3.x;
                    float a = acc[m][j];
                    a = fmaf(ev.x, waj0[j], a);
                    a = fmaf(ev.y, waj1[j], a);
                    a = fmaf(ev.z, waj2[j], a);
                    a = fmaf(ev.w, waj3[j], a);
                    a = fmaf(ax, wdj0[j], a);
                    a = fmaf(ay, wdj1[j], a);
                    a = fmaf(az, wdj2[j], a);
                    a = fmaf(aw, wdj3[j], a);
                    acc[m][j] = a;
                }
            }
        }
        // epilogue: logit per row via 32-lane reduce (spec_b2 dropped)
        float4 bn = *(const float4*)(s_bias + wq * H + jw0);
        float4 w2 = *(const float4*)(specW2 + jw0);
#pragma unroll
        for (int m = 0; m < 8; m++) {
            float p = 0.f;
            p += fmaxf(acc[m][0] + bn.x, 0.f) * w2.x;
            p += fmaxf(acc[m][1] + bn.y, 0.f) * w2.y;
            p += fmaxf(acc[m][2] + bn.z, 0.f) * w2.z;
            p += fmaxf(acc[m][3] + bn.w, 0.f) * w2.w;
#pragma unroll
            for (int off = 1; off < 32; off <<= 1) p += __shfl_xor(p, off, 64);
            if (jl == 0) s_logits[mb2 + m] = p;
        }
    }
    __syncthreads();

    // ---- stage 8: finalize (R threads: one per n-row) ----
    if (tid < R && (n0 + tid) < N) {
        const int r = tid;
        const int n = n0 + r;
        float s = s_dred[r] + defB2[0];
        out[(size_t)N * E + n] = 1.f / (1.f + expf(-s));
        int k = tkPtr[0];
        if (k < 1) k = 1;
        if (k > E - 1) k = E - 1;
        unsigned chosen = 0u;
        for (int kk = 0; kk < k; kk++) {
            float bv = -INFINITY;
            int bi = 0;
            for (int e = 0; e < E; e++) {
                if (e == fi || ((chosen >> e) & 1u)) continue;
                float v = s_logits[r * E + e];
                if (v > bv) { bv = v; bi = e; }
            }
            chosen |= (1u << bi);
        }
        float mx = -INFINITY;
        for (int e = 0; e < E; e++)
            if ((chosen >> e) & 1u) { float v = s_logits[r * E + e]; if (v > mx) mx = v; }
        float ssum = 0.f;
        for (int e = 0; e < E; e++)
            if ((chosen >> e) & 1u) ssum += expf(s_logits[r * E + e] - mx);
        float inv = 1.f / ssum;
        for (int e = 0; e < E; e++) {
            float wv = 0.f;
            if ((chosen >> e) & 1u) wv = expf(s_logits[r * E + e] - mx) * inv;
            out[(size_t)n * E + e] = wv;
        }
    }
}

extern "C" void kernel_launch(void* const* d_in, const int* in_sizes, int n_in,
                              void* d_out, int out_size, void* d_ws, size_t ws_size,
                              hipStream_t stream) {
    (void)n_in; (void)out_size;
    const float* tokens = (const float*)d_in[0];
    const float* encW1  = (const float*)d_in[1];
    const float* encB1  = (const float*)d_in[2];
    const float* encW2  = (const float*)d_in[3];
    const float* encB2  = (const float*)d_in[4];
    const float* specW1 = (const float*)d_in[5];
    const float* specB1 = (const float*)d_in[6];
    const float* specW2 = (const float*)d_in[7];
    // d_in[8] = spec_b2 (unused: softmax is shift-invariant)
    const float* defW1  = (const float*)d_in[9];
    const float* defB1  = (const float*)d_in[10];
    const float* defW2  = (const float*)d_in[11];
    const float* defB2  = (const float*)d_in[12];
    const int*   fiPtr  = (const int*)d_in[13];
    const int*   tkPtr  = (const int*)d_in[14];
    float* out = (float*)d_out;

    const int N = in_sizes[0] / (E * D);
    const int grid = (N + R - 1) / R;
    const bool useWs = (d_ws != nullptr) && (ws_size >= (size_t)(H * H * sizeof(float)));

    if (useWs) {
        wabc_prep<<<(H * H + 255) / 256, 256, 0, stream>>>(specW1, (float*)d_ws);
        router_kernel<true><<<grid, 256, 0, stream>>>(
            tokens, encW1, encB1, encW2, encB2, specW1, specB1, specW2,
            defW1, defB1, defW2, defB2, fiPtr, tkPtr, (const float*)d_ws, out, N);
    } else {
        router_kernel<false><<<grid, 256, 0, stream>>>(
            tokens, encW1, encB1, encW2, encB2, specW1, specB1, specW2,
            defW1, defB1, defW2, defB2, fiPtr, tkPtr, nullptr, out, N);
    }
}